// Round 1
// baseline (325.770 us; speedup 1.0000x reference)
//
#include <hip/hip_runtime.h>
#include <math.h>

// ---------- types ----------
typedef __attribute__((ext_vector_type(8))) short   short8;   // 8 bf16 = 4 VGPRs (MFMA A/B frag)
typedef __attribute__((ext_vector_type(4))) float   f32x4;    // MFMA C/D frag
typedef __attribute__((ext_vector_type(4))) float   float4v;
typedef __attribute__((ext_vector_type(8))) unsigned short ushort8;
typedef __attribute__((ext_vector_type(4))) unsigned short ushort4v;

#define NDIM 4096

// fp32 -> bf16, round-to-nearest-even (matches __float2bfloat16 / XLA cast)
__device__ __forceinline__ unsigned short f2bf(float f) {
  unsigned u = __builtin_bit_cast(unsigned, f);
  u += 0x7fffu + ((u >> 16) & 1u);
  return (unsigned short)(u >> 16);
}

// async global->LDS DMA, 16B/lane. LDS dest must be wave-uniform base + lane*16.
__device__ __forceinline__ void gload_lds16(const unsigned short* g, unsigned short* l) {
  __builtin_amdgcn_global_load_lds(
      (const __attribute__((address_space(1))) void*)g,
      (__attribute__((address_space(3))) void*)l, 16, 0, 0);
}

// ---------- pass 1: A fp32 -> bf16 (row-major preserved) ----------
__global__ void convert_bf16(const float* __restrict__ in, unsigned short* __restrict__ out) {
  int i = (blockIdx.x * blockDim.x + threadIdx.x) * 8;
  float4v a = *(const float4v*)(in + i);
  float4v b = *(const float4v*)(in + i + 4);
  ushort8 o;
  o[0] = f2bf(a[0]); o[1] = f2bf(a[1]); o[2] = f2bf(a[2]); o[3] = f2bf(a[3]);
  o[4] = f2bf(b[0]); o[5] = f2bf(b[1]); o[6] = f2bf(b[2]); o[7] = f2bf(b[3]);
  *(ushort8*)(out + i) = o;
}

// ---------- pass 2: W (K x N, fp32) -> Wt (N x K, bf16) ----------
// 64x64 tile through LDS (+1 pad), block (64,4).
__global__ void conv_transpose(const float* __restrict__ W, unsigned short* __restrict__ Wt) {
  __shared__ float tile[64][65];
  int n0 = blockIdx.x * 64, k0 = blockIdx.y * 64;
  int x = threadIdx.x;        // 0..63
  int y = threadIdx.y;        // 0..3
#pragma unroll
  for (int i = 0; i < 16; ++i) {
    int k = y + i * 4;
    tile[k][x] = W[(size_t)(k0 + k) * NDIM + n0 + x];   // coalesced along n
  }
  __syncthreads();
  int t = y * 64 + x;         // 0..255
#pragma unroll
  for (int i = 0; i < 4; ++i) {
    int c  = t + i * 256;     // 0..1023 chunk id
    int n  = c >> 4;          // 0..63
    int kc = (c & 15) * 4;    // 0,4,...,60
    ushort4v v;
    v[0] = f2bf(tile[kc + 0][n]);
    v[1] = f2bf(tile[kc + 1][n]);
    v[2] = f2bf(tile[kc + 2][n]);
    v[3] = f2bf(tile[kc + 3][n]);
    *(ushort4v*)&Wt[(size_t)(n0 + n) * NDIM + k0 + kc] = v;  // coalesced along k, 8B
  }
}

// ---------- pass 3: bf16 GEMM (B^T layout), 128x128 tile, BK=32, fused quant ----------
// C[m][n] = rintf(sum_k A[m][k]*Bt[n][k] * 256)/256 + rintf(bias[n]*256)/256
__global__ void gemm_bt_quant(const unsigned short* __restrict__ A,
                              const unsigned short* __restrict__ Bt,
                              const float* __restrict__ bias,
                              float* __restrict__ C) {
  __shared__ unsigned short As[128 * 32];   // row-major [m][k], 8KB
  __shared__ unsigned short Bs[128 * 32];   // row-major [n][k], 8KB

  const int tid  = threadIdx.x;
  const int lane = tid & 63;
  const int wid  = tid >> 6;                // 4 waves, 2x2
  const int wm   = (wid >> 1) * 64;
  const int wn   = (wid & 1) * 64;
  const int m0   = blockIdx.y * 128;
  const int n0   = blockIdx.x * 128;

  // staging: chunk tid covers 16B = 8 bf16; row = tid/4, kchunk = (tid%4)*8
  const int srow = tid >> 2;
  const int scol = (tid & 3) * 8;
  const unsigned short* Ag0 = A  + (size_t)(m0 + srow)      * NDIM + scol;
  const unsigned short* Ag1 = A  + (size_t)(m0 + 64 + srow) * NDIM + scol;
  const unsigned short* Bg0 = Bt + (size_t)(n0 + srow)      * NDIM + scol;
  const unsigned short* Bg1 = Bt + (size_t)(n0 + 64 + srow) * NDIM + scol;
  unsigned short* As0 = &As[tid * 8];          // byte offset tid*16 (lane-contiguous per wave)
  unsigned short* As1 = &As[2048 + tid * 8];
  unsigned short* Bs0 = &Bs[tid * 8];
  unsigned short* Bs1 = &Bs[2048 + tid * 8];

  // fragment read coords: A-frag lane l -> row (l&15), k (l>>4)*8..+8
  const int frow = lane & 15;
  const int fk   = (lane >> 4) * 8;

  f32x4 acc[4][4] = {};

  for (int kt = 0; kt < NDIM; kt += 32) {
    gload_lds16(Ag0 + kt, As0);
    gload_lds16(Ag1 + kt, As1);
    gload_lds16(Bg0 + kt, Bs0);
    gload_lds16(Bg1 + kt, Bs1);
    __syncthreads();   // compiler emits vmcnt(0) drain before s_barrier

    short8 af[4], bfr[4];
#pragma unroll
    for (int i = 0; i < 4; ++i)
      af[i] = *(const short8*)&As[(wm + i * 16 + frow) * 32 + fk];
#pragma unroll
    for (int j = 0; j < 4; ++j)
      bfr[j] = *(const short8*)&Bs[(wn + j * 16 + frow) * 32 + fk];
#pragma unroll
    for (int i = 0; i < 4; ++i)
#pragma unroll
      for (int j = 0; j < 4; ++j)
        acc[i][j] = __builtin_amdgcn_mfma_f32_16x16x32_bf16(af[i], bfr[j], acc[i][j], 0, 0, 0);

    __syncthreads();   // all waves done reading LDS before next overwrite
  }

  // epilogue: C/D layout col = lane&15, row = (lane>>4)*4 + reg  [m89-verified]
  const float inv = 1.0f / 256.0f;
  const int colb = n0 + wn + (lane & 15);
  const int rowb = m0 + wm + (lane >> 4) * 4;
#pragma unroll
  for (int j = 0; j < 4; ++j) {
    const int col = colb + j * 16;
    const float qb = rintf(bias[col] * 256.0f) * inv;
#pragma unroll
    for (int i = 0; i < 4; ++i) {
      float* Cp = C + (size_t)(rowb + i * 16) * NDIM + col;
#pragma unroll
      for (int r = 0; r < 4; ++r)
        Cp[(size_t)r * NDIM] = rintf(acc[i][j][r] * 256.0f) * inv + qb;
    }
  }
}

// ---------- fallback (ws too small): fp32 tiled GEMM, exact ----------
__global__ void gemm_fb(const float* __restrict__ A, const float* __restrict__ W,
                        const float* __restrict__ bias, float* __restrict__ C) {
  __shared__ float As[32][33], Ws[32][33];
  int tx = threadIdx.x, ty = threadIdx.y;     // (32,8)
  int m0 = blockIdx.y * 32, n0 = blockIdx.x * 32;
  float acc[4] = {0.f, 0.f, 0.f, 0.f};
  for (int k0 = 0; k0 < NDIM; k0 += 32) {
#pragma unroll
    for (int i = 0; i < 4; ++i) {
      int r = ty + i * 8;
      As[r][tx] = A[(size_t)(m0 + r) * NDIM + k0 + tx];
      Ws[r][tx] = W[(size_t)(k0 + r) * NDIM + n0 + tx];
    }
    __syncthreads();
#pragma unroll
    for (int k = 0; k < 32; ++k) {
      float wv = Ws[k][tx];
#pragma unroll
      for (int i = 0; i < 4; ++i) acc[i] += As[ty + i * 8][k] * wv;
    }
    __syncthreads();
  }
  float qb = rintf(bias[n0 + tx] * 256.0f) * (1.0f / 256.0f);
#pragma unroll
  for (int i = 0; i < 4; ++i)
    C[(size_t)(m0 + ty + i * 8) * NDIM + n0 + tx] =
        rintf(acc[i] * 256.0f) * (1.0f / 256.0f) + qb;
}

extern "C" void kernel_launch(void* const* d_in, const int* in_sizes, int n_in,
                              void* d_out, int out_size, void* d_ws, size_t ws_size,
                              hipStream_t stream) {
  const float* A    = (const float*)d_in[0];
  const float* W    = (const float*)d_in[1];
  const float* bias = (const float*)d_in[2];
  float* C = (float*)d_out;
  const size_t nElem = (size_t)NDIM * NDIM;

  if (ws_size >= nElem * 4) {   // need 2 bf16 matrices = 64 MB
    unsigned short* Abf = (unsigned short*)d_ws;
    unsigned short* Wt  = Abf + nElem;
    convert_bf16<<<(int)(nElem / 8 / 256), 256, 0, stream>>>(A, Abf);
    conv_transpose<<<dim3(64, 64), dim3(64, 4), 0, stream>>>(W, Wt);
    gemm_bt_quant<<<dim3(32, 32), 256, 0, stream>>>(Abf, Wt, bias, C);
  } else {
    gemm_fb<<<dim3(128, 128), dim3(32, 8), 0, stream>>>(A, W, bias, C);
  }
}

// Round 3
// 324.253 us; speedup vs baseline: 1.0047x; 1.0047x over previous
//
#include <hip/hip_runtime.h>
#include <math.h>

// ---------- types ----------
typedef __attribute__((ext_vector_type(8))) short   short8;   // 8 bf16 = 4 VGPRs (MFMA A/B frag)
typedef __attribute__((ext_vector_type(4))) float   f32x4;    // MFMA C/D frag
typedef __attribute__((ext_vector_type(4))) float   float4v;
typedef __attribute__((ext_vector_type(8))) unsigned short ushort8;
typedef __attribute__((ext_vector_type(4))) unsigned short ushort4v;

#define NDIM 4096

// fp32 -> bf16, round-to-nearest-even (matches __float2bfloat16 / XLA cast)
__device__ __forceinline__ unsigned short f2bf(float f) {
  unsigned u = __builtin_bit_cast(unsigned, f);
  u += 0x7fffu + ((u >> 16) & 1u);
  return (unsigned short)(u >> 16);
}

// async global->LDS DMA, 16B/lane. LDS dest must be wave-uniform base + lane*16.
__device__ __forceinline__ void gload_lds16(const unsigned short* g, unsigned short* l) {
  __builtin_amdgcn_global_load_lds(
      (const __attribute__((address_space(1))) void*)g,
      (__attribute__((address_space(3))) void*)l, 16, 0, 0);
}

// ---------- pass 1: A fp32 -> bf16 (row-major preserved) ----------
// 32B read / 16B write per thread, fully coalesced.
__global__ void convert_bf16(const float* __restrict__ in, unsigned short* __restrict__ out) {
  int i = (blockIdx.x * blockDim.x + threadIdx.x) * 8;
  float4v a = *(const float4v*)(in + i);
  float4v b = *(const float4v*)(in + i + 4);
  ushort8 o;
  o[0] = f2bf(a[0]); o[1] = f2bf(a[1]); o[2] = f2bf(a[2]); o[3] = f2bf(a[3]);
  o[4] = f2bf(b[0]); o[5] = f2bf(b[1]); o[6] = f2bf(b[2]); o[7] = f2bf(b[3]);
  *(ushort8*)(out + i) = o;
}

// ---------- pass 2: W (K x N, fp32) -> Wt (N x K, bf16) ----------
// float4 global reads, convert to bf16 BEFORE LDS, ushort8 global writes.
// bf16 tile [64][68]: stride 68 keeps the 8B ds_write aligned; transposed u16
// reads are at worst 4-way bank conflicts -- negligible vs global latency.
// LAUNCH: <<<dim3(64,64), 256>>> (flat 256-thread block; R2 bug was 16384/blk).
__global__ void conv_transpose(const float* __restrict__ W, unsigned short* __restrict__ Wt) {
  __shared__ unsigned short tileb[64][68];
  const int n0 = blockIdx.x * 64, k0 = blockIdx.y * 64;
  const int t  = threadIdx.x;          // 0..255
  const int rr = t >> 4;               // 0..15
  const int cc = (t & 15) * 4;         // 0,4,...,60
#pragma unroll
  for (int i = 0; i < 4; ++i) {
    int k = rr + i * 16;
    float4v v = *(const float4v*)&W[(size_t)(k0 + k) * NDIM + n0 + cc];  // 16B coalesced
    ushort4v u;
    u[0] = f2bf(v[0]); u[1] = f2bf(v[1]); u[2] = f2bf(v[2]); u[3] = f2bf(v[3]);
    *(ushort4v*)&tileb[k][cc] = u;     // 8B aligned LDS store
  }
  __syncthreads();
#pragma unroll
  for (int i = 0; i < 2; ++i) {
    int c  = t + i * 256;              // 0..511
    int n  = c >> 3;                   // 0..63
    int kc = (c & 7) * 8;              // 0,8,...,56
    ushort8 v;
#pragma unroll
    for (int j = 0; j < 8; ++j) v[j] = tileb[kc + j][n];
    *(ushort8*)&Wt[(size_t)(n0 + n) * NDIM + k0 + kc] = v;  // 16B coalesced along k
  }
}

// ---------- pass 3: bf16 GEMM (B^T layout), 128x128 tile, BK=32, fused quant ----------
// C[m][n] = rintf(sum_k A[m][k]*Bt[n][k] * 256)/256 + rintf(bias[n]*256)/256
// Unchanged from R1: sits at the m97-structure plateau (35.5% MfmaUtil, 791 TF).
__global__ void gemm_bt_quant(const unsigned short* __restrict__ A,
                              const unsigned short* __restrict__ Bt,
                              const float* __restrict__ bias,
                              float* __restrict__ C) {
  __shared__ unsigned short As[128 * 32];   // row-major [m][k], 8KB
  __shared__ unsigned short Bs[128 * 32];   // row-major [n][k], 8KB

  const int tid  = threadIdx.x;
  const int lane = tid & 63;
  const int wid  = tid >> 6;                // 4 waves, 2x2
  const int wm   = (wid >> 1) * 64;
  const int wn   = (wid & 1) * 64;
  const int m0   = blockIdx.y * 128;
  const int n0   = blockIdx.x * 128;

  // staging: chunk tid covers 16B = 8 bf16; row = tid/4, kchunk = (tid%4)*8
  const int srow = tid >> 2;
  const int scol = (tid & 3) * 8;
  const unsigned short* Ag0 = A  + (size_t)(m0 + srow)      * NDIM + scol;
  const unsigned short* Ag1 = A  + (size_t)(m0 + 64 + srow) * NDIM + scol;
  const unsigned short* Bg0 = Bt + (size_t)(n0 + srow)      * NDIM + scol;
  const unsigned short* Bg1 = Bt + (size_t)(n0 + 64 + srow) * NDIM + scol;
  unsigned short* As0 = &As[tid * 8];          // byte offset tid*16 (lane-contiguous per wave)
  unsigned short* As1 = &As[2048 + tid * 8];
  unsigned short* Bs0 = &Bs[tid * 8];
  unsigned short* Bs1 = &Bs[2048 + tid * 8];

  // fragment read coords: A-frag lane l -> row (l&15), k (l>>4)*8..+8
  const int frow = lane & 15;
  const int fk   = (lane >> 4) * 8;

  f32x4 acc[4][4] = {};

  for (int kt = 0; kt < NDIM; kt += 32) {
    gload_lds16(Ag0 + kt, As0);
    gload_lds16(Ag1 + kt, As1);
    gload_lds16(Bg0 + kt, Bs0);
    gload_lds16(Bg1 + kt, Bs1);
    __syncthreads();   // compiler emits vmcnt(0) drain before s_barrier

    short8 af[4], bfr[4];
#pragma unroll
    for (int i = 0; i < 4; ++i)
      af[i] = *(const short8*)&As[(wm + i * 16 + frow) * 32 + fk];
#pragma unroll
    for (int j = 0; j < 4; ++j)
      bfr[j] = *(const short8*)&Bs[(wn + j * 16 + frow) * 32 + fk];
#pragma unroll
    for (int i = 0; i < 4; ++i)
#pragma unroll
      for (int j = 0; j < 4; ++j)
        acc[i][j] = __builtin_amdgcn_mfma_f32_16x16x32_bf16(af[i], bfr[j], acc[i][j], 0, 0, 0);

    __syncthreads();   // all waves done reading LDS before next overwrite
  }

  // epilogue: C/D layout col = lane&15, row = (lane>>4)*4 + reg  [m89-verified]
  const float inv = 1.0f / 256.0f;
  const int colb = n0 + wn + (lane & 15);
  const int rowb = m0 + wm + (lane >> 4) * 4;
#pragma unroll
  for (int j = 0; j < 4; ++j) {
    const int col = colb + j * 16;
    const float qb = rintf(bias[col] * 256.0f) * inv;
#pragma unroll
    for (int i = 0; i < 4; ++i) {
      float* Cp = C + (size_t)(rowb + i * 16) * NDIM + col;
#pragma unroll
      for (int r = 0; r < 4; ++r)
        Cp[(size_t)r * NDIM] = rintf(acc[i][j][r] * 256.0f) * inv + qb;
    }
  }
}

// ---------- fallback (ws too small): fp32 tiled GEMM, exact ----------
__global__ void gemm_fb(const float* __restrict__ A, const float* __restrict__ W,
                        const float* __restrict__ bias, float* __restrict__ C) {
  __shared__ float As[32][33], Ws[32][33];
  int tx = threadIdx.x, ty = threadIdx.y;     // (32,8)
  int m0 = blockIdx.y * 32, n0 = blockIdx.x * 32;
  float acc[4] = {0.f, 0.f, 0.f, 0.f};
  for (int k0 = 0; k0 < NDIM; k0 += 32) {
#pragma unroll
    for (int i = 0; i < 4; ++i) {
      int r = ty + i * 8;
      As[r][tx] = A[(size_t)(m0 + r) * NDIM + k0 + tx];
      Ws[r][tx] = W[(size_t)(k0 + r) * NDIM + n0 + tx];
    }
    __syncthreads();
#pragma unroll
    for (int k = 0; k < 32; ++k) {
      float wv = Ws[k][tx];
#pragma unroll
      for (int i = 0; i < 4; ++i) acc[i] += As[ty + i * 8][k] * wv;
    }
    __syncthreads();
  }
  float qb = rintf(bias[n0 + tx] * 256.0f) * (1.0f / 256.0f);
#pragma unroll
  for (int i = 0; i < 4; ++i)
    C[(size_t)(m0 + ty + i * 8) * NDIM + n0 + tx] =
        rintf(acc[i] * 256.0f) * (1.0f / 256.0f) + qb;
}

extern "C" void kernel_launch(void* const* d_in, const int* in_sizes, int n_in,
                              void* d_out, int out_size, void* d_ws, size_t ws_size,
                              hipStream_t stream) {
  const float* A    = (const float*)d_in[0];
  const float* W    = (const float*)d_in[1];
  const float* bias = (const float*)d_in[2];
  float* C = (float*)d_out;
  const size_t nElem = (size_t)NDIM * NDIM;

  if (ws_size >= nElem * 4) {   // need 2 bf16 matrices = 64 MB
    unsigned short* Abf = (unsigned short*)d_ws;
    unsigned short* Wt  = Abf + nElem;
    convert_bf16<<<(int)(nElem / 8 / 256), 256, 0, stream>>>(A, Abf);
    conv_transpose<<<dim3(64, 64), 256, 0, stream>>>(W, Wt);
    gemm_bt_quant<<<dim3(32, 32), 256, 0, stream>>>(Abf, Wt, bias, C);
  } else {
    gemm_fb<<<dim3(128, 128), dim3(32, 8), 0, stream>>>(A, W, bias, C);
  }
}

// Round 4
// 311.820 us; speedup vs baseline: 1.0447x; 1.0399x over previous
//
#include <hip/hip_runtime.h>
#include <math.h>

// ---------- types ----------
typedef __attribute__((ext_vector_type(8))) short   short8;   // 8 bf16 = 4 VGPRs (MFMA A/B frag)
typedef __attribute__((ext_vector_type(4))) float   f32x4;    // MFMA C/D frag
typedef __attribute__((ext_vector_type(4))) float   float4v;
typedef __attribute__((ext_vector_type(8))) unsigned short ushort8;
typedef __attribute__((ext_vector_type(4))) unsigned short ushort4v;

#define NDIM 4096
#define BK   64

// fp32 -> bf16, round-to-nearest-even (matches __float2bfloat16 / XLA cast)
__device__ __forceinline__ unsigned short f2bf(float f) {
  unsigned u = __builtin_bit_cast(unsigned, f);
  u += 0x7fffu + ((u >> 16) & 1u);
  return (unsigned short)(u >> 16);
}

// async global->LDS DMA, 16B/lane. LDS dest must be wave-uniform base + lane*16.
__device__ __forceinline__ void gload_lds16(const unsigned short* g, unsigned short* l) {
  __builtin_amdgcn_global_load_lds(
      (const __attribute__((address_space(1))) void*)g,
      (__attribute__((address_space(3))) void*)l, 16, 0, 0);
}

// ---------- fused prep: A fp32->bf16 (blocks 0..8191) ; W -> Wt bf16 (blocks 8192..12287) ----------
// The two jobs are independent; fusing them into one grid lets them overlap
// (two same-stream kernels would serialize).
__global__ void prep(const float* __restrict__ A, unsigned short* __restrict__ Abf,
                     const float* __restrict__ W, unsigned short* __restrict__ Wt) {
  __shared__ unsigned short tileb[64][68];   // used by transpose branch only
  const int t = threadIdx.x;                 // 0..255
  if (blockIdx.x < 8192) {
    // --- convert branch: 32B read / 16B write per thread, fully coalesced ---
    int i = (blockIdx.x * 256 + t) * 8;
    float4v a = *(const float4v*)(A + i);
    float4v b = *(const float4v*)(A + i + 4);
    ushort8 o;
    o[0] = f2bf(a[0]); o[1] = f2bf(a[1]); o[2] = f2bf(a[2]); o[3] = f2bf(a[3]);
    o[4] = f2bf(b[0]); o[5] = f2bf(b[1]); o[6] = f2bf(b[2]); o[7] = f2bf(b[3]);
    *(ushort8*)(Abf + i) = o;
  } else {
    // --- transpose branch: W (K x N) -> Wt (N x K), 64x64 tile via LDS ---
    int b  = blockIdx.x - 8192;
    int n0 = (b & 63) * 64, k0 = (b >> 6) * 64;
    const int rr = t >> 4;               // 0..15
    const int cc = (t & 15) * 4;         // 0,4,...,60
#pragma unroll
    for (int i = 0; i < 4; ++i) {
      int k = rr + i * 16;
      float4v v = *(const float4v*)&W[(size_t)(k0 + k) * NDIM + n0 + cc];  // 16B coalesced
      ushort4v u;
      u[0] = f2bf(v[0]); u[1] = f2bf(v[1]); u[2] = f2bf(v[2]); u[3] = f2bf(v[3]);
      *(ushort4v*)&tileb[k][cc] = u;     // 8B aligned LDS store
    }
    __syncthreads();
#pragma unroll
    for (int i = 0; i < 2; ++i) {
      int c  = t + i * 256;              // 0..511
      int n  = c >> 3;                   // 0..63
      int kc = (c & 7) * 8;              // 0,8,...,56
      ushort8 v;
#pragma unroll
      for (int j = 0; j < 8; ++j) v[j] = tileb[kc + j][n];
      *(ushort8*)&Wt[(size_t)(n0 + n) * NDIM + k0 + kc] = v;  // 16B coalesced along k
    }
  }
}

// ---------- gemm: 128x128 tile, BK=64 (barrier count halved vs BK=32), fused quant ----------
// LDS layout swizzle: element [row][k] stored at row*64 + (chunk ^ ((row&1)*4))*8 + (k&7)
// (chunk = k>>3). Applied on the staging SOURCE address (DMA dest must stay lane-linear),
// undone in fragment reads via ko = fk + 32*(h ^ (frow&1)). This restores the
// 8-accesses/bank minimum that a naive 128B row stride would break (16 banks only).
// C[m][n] = rintf(sum_k A[m][k]*Bt[n][k] * 256)/256 + rintf(bias[n]*256)/256
__global__ __launch_bounds__(256, 4)
void gemm_bt_quant(const unsigned short* __restrict__ A,
                   const unsigned short* __restrict__ Bt,
                   const float* __restrict__ bias,
                   float* __restrict__ C) {
  __shared__ unsigned short As[128 * BK];   // 16KB
  __shared__ unsigned short Bs[128 * BK];   // 16KB

  const int tid  = threadIdx.x;
  const int lane = tid & 63;
  const int wid  = tid >> 6;                // 4 waves, 2x2
  const int wm   = (wid >> 1) * 64;
  const int wn   = (wid & 1) * 64;
  const int m0   = blockIdx.y * 128;
  const int n0   = blockIdx.x * 128;

  // staging: 2048 chunks of 8 u16 per matrix, 256 threads x 4 passes (p = row/32).
  // slot q = p*256 + tid -> row = q>>3, dest chunk c' = q&7; source chunk c = c' ^ ((row&1)*4).
  const int srow = tid >> 3;                          // 0..31 (row within pass group)
  const int sc   = (tid & 7) ^ ((srow & 1) * 4);      // swizzled source chunk
  const unsigned short* Ag = A  + (size_t)(m0 + srow) * NDIM + sc * 8;
  const unsigned short* Bg = Bt + (size_t)(n0 + srow) * NDIM + sc * 8;

  // fragment coords: lane holds [m=frow][k = 32h + fk + j]; physical k-offset swizzled by row parity
  const int frow = lane & 15;
  const int fk   = (lane >> 4) * 8;
  const int fpar = frow & 1;

  f32x4 acc[4][4] = {};

  for (int kt = 0; kt < NDIM; kt += BK) {
#pragma unroll
    for (int p = 0; p < 4; ++p) {
      gload_lds16(Ag + kt + (size_t)p * 32 * NDIM, &As[(p * 256 + tid) * 8]);
      gload_lds16(Bg + kt + (size_t)p * 32 * NDIM, &Bs[(p * 256 + tid) * 8]);
    }
    __syncthreads();   // drain DMA (compiler emits vmcnt(0) before s_barrier)

#pragma unroll
    for (int h = 0; h < 2; ++h) {
      const int ko = fk + 32 * (h ^ fpar);   // physical offset of logical K-slice 32h+fk
      short8 af[4], bfr[4];
#pragma unroll
      for (int i = 0; i < 4; ++i)
        af[i] = *(const short8*)&As[(wm + i * 16 + frow) * BK + ko];
#pragma unroll
      for (int j = 0; j < 4; ++j)
        bfr[j] = *(const short8*)&Bs[(wn + j * 16 + frow) * BK + ko];
#pragma unroll
      for (int i = 0; i < 4; ++i)
#pragma unroll
        for (int j = 0; j < 4; ++j)
          acc[i][j] = __builtin_amdgcn_mfma_f32_16x16x32_bf16(af[i], bfr[j], acc[i][j], 0, 0, 0);
    }

    __syncthreads();   // all waves done reading LDS before next overwrite
  }

  // epilogue: C/D layout col = lane&15, row = (lane>>4)*4 + reg  [m89-verified]
  const float inv = 1.0f / 256.0f;
  const int colb = n0 + wn + (lane & 15);
  const int rowb = m0 + wm + (lane >> 4) * 4;
#pragma unroll
  for (int j = 0; j < 4; ++j) {
    const int col = colb + j * 16;
    const float qb = rintf(bias[col] * 256.0f) * inv;
#pragma unroll
    for (int i = 0; i < 4; ++i) {
      float* Cp = C + (size_t)(rowb + i * 16) * NDIM + col;
#pragma unroll
      for (int r = 0; r < 4; ++r)
        Cp[(size_t)r * NDIM] = rintf(acc[i][j][r] * 256.0f) * inv + qb;
    }
  }
}

// ---------- fallback (ws too small): fp32 tiled GEMM, exact ----------
__global__ void gemm_fb(const float* __restrict__ A, const float* __restrict__ W,
                        const float* __restrict__ bias, float* __restrict__ C) {
  __shared__ float As[32][33], Ws[32][33];
  int tx = threadIdx.x, ty = threadIdx.y;     // (32,8)
  int m0 = blockIdx.y * 32, n0 = blockIdx.x * 32;
  float acc[4] = {0.f, 0.f, 0.f, 0.f};
  for (int k0 = 0; k0 < NDIM; k0 += 32) {
#pragma unroll
    for (int i = 0; i < 4; ++i) {
      int r = ty + i * 8;
      As[r][tx] = A[(size_t)(m0 + r) * NDIM + k0 + tx];
      Ws[r][tx] = W[(size_t)(k0 + r) * NDIM + n0 + tx];
    }
    __syncthreads();
#pragma unroll
    for (int k = 0; k < 32; ++k) {
      float wv = Ws[k][tx];
#pragma unroll
      for (int i = 0; i < 4; ++i) acc[i] += As[ty + i * 8][k] * wv;
    }
    __syncthreads();
  }
  float qb = rintf(bias[n0 + tx] * 256.0f) * (1.0f / 256.0f);
#pragma unroll
  for (int i = 0; i < 4; ++i)
    C[(size_t)(m0 + ty + i * 8) * NDIM + n0 + tx] =
        rintf(acc[i] * 256.0f) * (1.0f / 256.0f) + qb;
}

extern "C" void kernel_launch(void* const* d_in, const int* in_sizes, int n_in,
                              void* d_out, int out_size, void* d_ws, size_t ws_size,
                              hipStream_t stream) {
  const float* A    = (const float*)d_in[0];
  const float* W    = (const float*)d_in[1];
  const float* bias = (const float*)d_in[2];
  float* C = (float*)d_out;
  const size_t nElem = (size_t)NDIM * NDIM;

  if (ws_size >= nElem * 4) {   // need 2 bf16 matrices = 64 MB
    unsigned short* Abf = (unsigned short*)d_ws;
    unsigned short* Wt  = Abf + nElem;
    prep<<<8192 + 4096, 256, 0, stream>>>(A, Abf, W, Wt);
    gemm_bt_quant<<<dim3(32, 32), 256, 0, stream>>>(Abf, Wt, bias, C);
  } else {
    gemm_fb<<<dim3(128, 128), dim3(32, 8), 0, stream>>>(A, W, bias, C);
  }
}

// Round 5
// 299.520 us; speedup vs baseline: 1.0876x; 1.0411x over previous
//
#include <hip/hip_runtime.h>
#include <math.h>

// ---------- types ----------
typedef __attribute__((ext_vector_type(8)))  short  short8;   // 8 bf16 (4 VGPRs) MFMA A/B frag
typedef __attribute__((ext_vector_type(16))) float  f32x16;   // 32x32 MFMA C/D frag
typedef __attribute__((ext_vector_type(4)))  float  float4v;
typedef __attribute__((ext_vector_type(8)))  unsigned short ushort8;
typedef __attribute__((ext_vector_type(4)))  unsigned short ushort4v;

#define NDIM 4096
#define BM 256
#define BN 128
#define BK 64

// fp32 -> bf16, round-to-nearest-even
__device__ __forceinline__ unsigned short f2bf(float f) {
  unsigned u = __builtin_bit_cast(unsigned, f);
  u += 0x7fffu + ((u >> 16) & 1u);
  return (unsigned short)(u >> 16);
}

// async global->LDS DMA, 16B/lane. LDS dest must be wave-uniform base + lane*16.
__device__ __forceinline__ void gload_lds16(const unsigned short* g, unsigned short* l) {
  __builtin_amdgcn_global_load_lds(
      (const __attribute__((address_space(1))) void*)g,
      (__attribute__((address_space(3))) void*)l, 16, 0, 0);
}

// ---------- fused prep: A fp32->bf16 (blocks 0..8191) ; W -> Wt bf16 (8192..12287) ----------
__global__ void prep(const float* __restrict__ A, unsigned short* __restrict__ Abf,
                     const float* __restrict__ W, unsigned short* __restrict__ Wt) {
  __shared__ unsigned short tileb[64][68];
  const int t = threadIdx.x;                 // 0..255
  if (blockIdx.x < 8192) {
    int i = (blockIdx.x * 256 + t) * 8;
    float4v a = *(const float4v*)(A + i);
    float4v b = *(const float4v*)(A + i + 4);
    ushort8 o;
    o[0] = f2bf(a[0]); o[1] = f2bf(a[1]); o[2] = f2bf(a[2]); o[3] = f2bf(a[3]);
    o[4] = f2bf(b[0]); o[5] = f2bf(b[1]); o[6] = f2bf(b[2]); o[7] = f2bf(b[3]);
    *(ushort8*)(Abf + i) = o;
  } else {
    int b  = blockIdx.x - 8192;
    int n0 = (b & 63) * 64, k0 = (b >> 6) * 64;
    const int rr = t >> 4;
    const int cc = (t & 15) * 4;
#pragma unroll
    for (int i = 0; i < 4; ++i) {
      int k = rr + i * 16;
      float4v v = *(const float4v*)&W[(size_t)(k0 + k) * NDIM + n0 + cc];
      ushort4v u;
      u[0] = f2bf(v[0]); u[1] = f2bf(v[1]); u[2] = f2bf(v[2]); u[3] = f2bf(v[3]);
      *(ushort4v*)&tileb[k][cc] = u;
    }
    __syncthreads();
#pragma unroll
    for (int i = 0; i < 2; ++i) {
      int c  = t + i * 256;
      int n  = c >> 3;
      int kc = (c & 7) * 8;
      ushort8 v;
#pragma unroll
      for (int j = 0; j < 8; ++j) v[j] = tileb[kc + j][n];
      *(ushort8*)&Wt[(size_t)(n0 + n) * NDIM + k0 + kc] = v;
    }
  }
}

// ---------- gemm: 256x128 block, wave tile 128x64, MFMA 32x32x16, XOR-8 swizzle ----------
// LDS-BW-bound analysis (R4 post-mortem): wave tile 128x64 raises FLOP/LDS-byte
// 32 -> 42.7; XOR-8 swizzle (chunk c of row r stored at c^(r&7)) makes every
// 8-consecutive-lane group of a b128 read cover all 32 banks -> conflict-free.
// Swizzle applied on DMA SOURCE address (dest must stay lane-linear), undone at
// fragment read. A-frag: A[m=lane&31][k=(lane>>5)*8+j]; C/D: col=lane&31,
// row=(reg&3)+8*(reg>>2)+4*(lane>>5) [m74/m101].
__global__ __launch_bounds__(256, 2)
void gemm_bt_quant(const unsigned short* __restrict__ A,
                   const unsigned short* __restrict__ Bt,
                   const float* __restrict__ bias,
                   float* __restrict__ C) {
  __shared__ unsigned short As[BM * BK];   // 32 KB
  __shared__ unsigned short Bs[BN * BK];   // 16 KB

  const int tid  = threadIdx.x;
  const int lane = tid & 63;
  const int wid  = tid >> 6;               // 4 waves, 2x2: wm in {0,128}, wn in {0,64}
  const int wm   = (wid >> 1) * 128;
  const int wn   = (wid & 1) * 64;
  const int m0   = blockIdx.y * BM;
  const int n0   = blockIdx.x * BN;

  // staging: slot s = p*256+tid -> dest row s>>3, dest chunk s&7;
  // source logical chunk = (s&7) ^ (row&7). Rows advance 32/pass (mult of 8),
  // so row&7 == (tid>>3)&7 for all passes.
  const int srow = tid >> 3;                     // 0..31
  const int sc   = (tid & 7) ^ (srow & 7);       // swizzled source chunk
  const unsigned short* Ag = A  + (size_t)(m0 + srow) * NDIM + sc * 8;
  const unsigned short* Bg = Bt + (size_t)(n0 + srow) * NDIM + sc * 8;

  const int fr = lane & 31;                // fragment row within 32-tile
  const int fh = lane >> 5;                // K-half selector
  const int fsw = fr & 7;                  // read-side swizzle (row&7)

  f32x16 acc[4][2] = {};

  for (int kt = 0; kt < NDIM; kt += BK) {
#pragma unroll
    for (int p = 0; p < 8; ++p)
      gload_lds16(Ag + kt + (size_t)(p * 32) * NDIM, &As[(p * 256 + tid) * 8]);
#pragma unroll
    for (int p = 0; p < 4; ++p)
      gload_lds16(Bg + kt + (size_t)(p * 32) * NDIM, &Bs[(p * 256 + tid) * 8]);
    __syncthreads();

#pragma unroll
    for (int h = 0; h < 4; ++h) {          // K16 steps within BK
      const int cph = (2 * h + fh) ^ fsw;  // physical chunk for this lane
      short8 af[4], bfr[2];
#pragma unroll
      for (int i = 0; i < 4; ++i)
        af[i] = *(const short8*)&As[(wm + i * 32 + fr) * BK + cph * 8];
#pragma unroll
      for (int j = 0; j < 2; ++j)
        bfr[j] = *(const short8*)&Bs[(wn + j * 32 + fr) * BK + cph * 8];
#pragma unroll
      for (int i = 0; i < 4; ++i)
#pragma unroll
        for (int j = 0; j < 2; ++j)
          acc[i][j] = __builtin_amdgcn_mfma_f32_32x32x16_bf16(af[i], bfr[j], acc[i][j], 0, 0, 0);
    }
    __syncthreads();
  }

  // epilogue: fused quant + bias
  const float inv = 1.0f / 256.0f;
#pragma unroll
  for (int j = 0; j < 2; ++j) {
    const int col = n0 + wn + j * 32 + fr;
    const float qb = rintf(bias[col] * 256.0f) * inv;
#pragma unroll
    for (int i = 0; i < 4; ++i) {
      const int rb = m0 + wm + i * 32 + 4 * fh;
#pragma unroll
      for (int r = 0; r < 16; ++r) {
        const int row = rb + (r & 3) + 8 * (r >> 2);
        C[(size_t)row * NDIM + col] = rintf(acc[i][j][r] * 256.0f) * inv + qb;
      }
    }
  }
}

// ---------- fallback (ws too small): fp32 tiled GEMM, exact ----------
__global__ void gemm_fb(const float* __restrict__ A, const float* __restrict__ W,
                        const float* __restrict__ bias, float* __restrict__ C) {
  __shared__ float As[32][33], Ws[32][33];
  int tx = threadIdx.x, ty = threadIdx.y;     // (32,8)
  int m0 = blockIdx.y * 32, n0 = blockIdx.x * 32;
  float acc[4] = {0.f, 0.f, 0.f, 0.f};
  for (int k0 = 0; k0 < NDIM; k0 += 32) {
#pragma unroll
    for (int i = 0; i < 4; ++i) {
      int r = ty + i * 8;
      As[r][tx] = A[(size_t)(m0 + r) * NDIM + k0 + tx];
      Ws[r][tx] = W[(size_t)(k0 + r) * NDIM + n0 + tx];
    }
    __syncthreads();
#pragma unroll
    for (int k = 0; k < 32; ++k) {
      float wv = Ws[k][tx];
#pragma unroll
      for (int i = 0; i < 4; ++i) acc[i] += As[ty + i * 8][k] * wv;
    }
    __syncthreads();
  }
  float qb = rintf(bias[n0 + tx] * 256.0f) * (1.0f / 256.0f);
#pragma unroll
  for (int i = 0; i < 4; ++i)
    C[(size_t)(m0 + ty + i * 8) * NDIM + n0 + tx] =
        rintf(acc[i] * 256.0f) * (1.0f / 256.0f) + qb;
}

extern "C" void kernel_launch(void* const* d_in, const int* in_sizes, int n_in,
                              void* d_out, int out_size, void* d_ws, size_t ws_size,
                              hipStream_t stream) {
  const float* A    = (const float*)d_in[0];
  const float* W    = (const float*)d_in[1];
  const float* bias = (const float*)d_in[2];
  float* C = (float*)d_out;
  const size_t nElem = (size_t)NDIM * NDIM;

  if (ws_size >= nElem * 4) {   // need 2 bf16 matrices = 64 MB
    unsigned short* Abf = (unsigned short*)d_ws;
    unsigned short* Wt  = Abf + nElem;
    prep<<<8192 + 4096, 256, 0, stream>>>(A, Abf, W, Wt);
    gemm_bt_quant<<<dim3(NDIM / BN, NDIM / BM), 256, 0, stream>>>(Abf, Wt, bias, C);
  } else {
    gemm_fb<<<dim3(128, 128), dim3(32, 8), 0, stream>>>(A, W, bias, C);
  }
}